// Round 6
// baseline (433.706 us; speedup 1.0000x reference)
//
#include <hip/hip_runtime.h>
#include <math.h>

// Problem constants (fixed by the reference).
#define BB 8
#define LL 12
#define TT 36
#define DD 1024
#define FF 3
#define CC 32
#define NDC 8               // 128-d slices in k_mq / k_out

// ---------------------------------------------------------------------------
// K1: partial scores, LDS-staged.
// grid (96, 8) = 768 blocks (3/CU, 12 waves/CU). 256 threads =
// (ds=8: 16-d sub) x (tq=4: t mod 4) x (cg=8: 4 channels).
// t processed in 5 chunks (8,8,8,8,4): coalesced global->LDS double-buffered
// staging (1KB distinct bytes per wave instr -- fixes R5's 32-byte broadcast
// loads), compute reads LDS (broadcast free; row stride 97 f4 => <=2-way
// bank aliasing). acc[9 tj][4 ci] in regs; shfl+LDS epilogue -> mqp.
// ---------------------------------------------------------------------------
__global__ __launch_bounds__(256, 3) void k_mq(const float* __restrict__ xl,
                                               const float* __restrict__ xh,
                                               const float* __restrict__ Wm,
                                               const float* __restrict__ bm,
                                               const float* __restrict__ Wq,
                                               const float* __restrict__ bq,
                                               float* __restrict__ mqp) {
  __shared__ float4 smem4[2 * 8 * 97];   // 24.8 KB; epilogue 'part' aliases it
  float* smem = (float*)smem4;

  const int bl  = blockIdx.x;
  const int dc  = blockIdx.y;            // 0..7
  const int tid = threadIdx.x;
  const int ds  = tid >> 5;              // 0..7 (16-d slice)
  const int r   = tid & 31;
  const int tq  = r >> 3;                // 0..3
  const int cg  = r & 7;                 // channels cg*4..cg*4+3

  float wmv[4][3], bmv[4];
  #pragma unroll
  for (int ci = 0; ci < 4; ++ci) {
    const int c = cg * 4 + ci;
    wmv[ci][0] = Wm[c*3+0]; wmv[ci][1] = Wm[c*3+1]; wmv[ci][2] = Wm[c*3+2];
    bmv[ci] = bm[c];
  }

  // q[ci][16 d] from x_local, in registers.
  float q[4][16];
  {
    const float4* xl4 = (const float4*)xl + ((size_t)bl * DD + dc*128 + ds*16) * 3 / 4;
    float4 xb4[12];
    #pragma unroll
    for (int i = 0; i < 12; ++i) xb4[i] = xl4[i];
    const float* x = (const float*)xb4;
    #pragma unroll
    for (int ci = 0; ci < 4; ++ci) {
      const int c = cg*4+ci;
      const float w0 = Wq[c*3], w1 = Wq[c*3+1], w2 = Wq[c*3+2], b0 = bq[c];
      #pragma unroll
      for (int k = 0; k < 16; ++k)
        q[ci][k] = fmaf(w0, x[k*3], fmaf(w1, x[k*3+1], fmaf(w2, x[k*3+2], b0)));
    }
  }

  float acc[9][4];
  #pragma unroll
  for (int j = 0; j < 9; ++j)
    #pragma unroll
    for (int ci = 0; ci < 4; ++ci) acc[j][ci] = 0.f;

  float4 sr[3]; int didx[3];
  float4* const buf4_0 = smem4;
  float4* const buf4_1 = smem4 + 8*97;

  auto issue = [&](int ck) {             // load chunk ck's f4s into sr
    const int n = ((ck < 4) ? 8 : 4) * 96;
    #pragma unroll
    for (int j = 0; j < 3; ++j) {
      const int idx = tid + j*256;
      if (idx < n) {
        const int t   = idx / 96;
        const int col = idx - t*96;
        sr[j] = ((const float4*)xh)[(size_t)(bl*TT + ck*8 + t) * 768 + (size_t)dc*96 + col];
        didx[j] = t*97 + col;
      }
    }
  };
  auto commit = [&](int ck, float4* buf) {
    const int n = ((ck < 4) ? 8 : 4) * 96;
    #pragma unroll
    for (int j = 0; j < 3; ++j) {
      const int idx = tid + j*256;
      if (idx < n) buf[didx[j]] = sr[j];
    }
  };
  auto dot_t = [&](const float4* buf, int tloc, float* a4) {
    const float4* row = buf + tloc*97 + ds*12;
    #pragma unroll
    for (int h = 0; h < 2; ++h) {        // two halves of 8 d (register pressure)
      float4 xb4[6];
      #pragma unroll
      for (int i = 0; i < 6; ++i) xb4[i] = row[h*6 + i];
      const float* x = (const float*)xb4;
      #pragma unroll
      for (int k = 0; k < 8; ++k) {
        const float x0 = x[k*3], x1 = x[k*3+1], x2 = x[k*3+2];
        const int d = h*8 + k;
        #pragma unroll
        for (int ci = 0; ci < 4; ++ci) {
          const float m = fmaf(wmv[ci][0], x0,
                          fmaf(wmv[ci][1], x1,
                          fmaf(wmv[ci][2], x2, bmv[ci])));
          a4[ci] = fmaf(m, q[ci][d], a4[ci]);
        }
      }
    }
  };

  issue(0); commit(0, buf4_0);
  issue(1);
  __syncthreads();                       // buf0 ready
  dot_t(buf4_0, tq,     acc[0]);
  dot_t(buf4_0, tq + 4, acc[1]);
  commit(1, buf4_1); issue(2);
  __syncthreads();                       // buf1 ready
  dot_t(buf4_1, tq,     acc[2]);
  dot_t(buf4_1, tq + 4, acc[3]);
  commit(2, buf4_0); issue(3);
  __syncthreads();
  dot_t(buf4_0, tq,     acc[4]);
  dot_t(buf4_0, tq + 4, acc[5]);
  commit(3, buf4_1); issue(4);
  __syncthreads();
  dot_t(buf4_1, tq,     acc[6]);
  dot_t(buf4_1, tq + 4, acc[7]);
  commit(4, buf4_0);
  __syncthreads();
  dot_t(buf4_0, tq, acc[8]);             // tail: t = 32 + tq
  __syncthreads();                       // before 'part' aliases smem

  // Epilogue: fold ds. shfl folds ds-pairs in-wave; LDS folds the 4 waves.
  const int w    = tid >> 6;
  const int lane = tid & 63;
  #pragma unroll
  for (int tj = 0; tj < 9; ++tj)
    #pragma unroll
    for (int ci = 0; ci < 4; ++ci) {
      float a = acc[tj][ci];
      a += __shfl_down(a, 32);
      if (lane < 32) smem[(w*32 + r) * 37 + ci*9 + tj] = a;  // stride 37: conflict-free
    }
  __syncthreads();
  for (int idx = tid; idx < 32*36; idx += 256) {
    const int r2 = idx / 36;
    const int u  = idx - r2*36;
    const float v = (smem[r2*37 + u]        + smem[1184 + r2*37 + u]) +
                    (smem[2368 + r2*37 + u] + smem[3552 + r2*37 + u]);
    const int ci = u / 9, tj = u - ci*9;
    const int cg2 = r2 & 7, tq2 = r2 >> 3;
    const int c = cg2*4 + ci, t = tj*4 + tq2;
    mqp[(((size_t)bl*TT + t) * NDC + dc) * CC + c] = v;
  }
}

// ---------------------------------------------------------------------------
// K2: reduce mqp over dc, relu+softmax over t, write att[bl][t][c]. grid(96).
// ---------------------------------------------------------------------------
__global__ __launch_bounds__(256) void k_soft(const float* __restrict__ mqp,
                                              float* __restrict__ att_g) {
  __shared__ float S[TT][CC];
  __shared__ float mxv[CC], inv[CC];
  const int bl = blockIdx.x;
  const int tid = threadIdx.x;

  for (int idx = tid; idx < TT * CC; idx += 256) {
    const int t = idx >> 5;
    const int c = idx & 31;
    const float* p = mqp + (((size_t)bl * TT + t) * NDC) * CC + c;
    float v = 0.f;
    #pragma unroll
    for (int j = 0; j < NDC; ++j) v += p[j * CC];
    S[t][c] = fmaxf(v, 0.f);
  }
  __syncthreads();
  if (tid < CC) {
    const int c = tid;
    float mx = 0.f;
    #pragma unroll
    for (int t = 0; t < TT; ++t) mx = fmaxf(mx, S[t][c]);
    float ssum = 0.f;
    #pragma unroll
    for (int t = 0; t < TT; ++t) ssum += __expf(S[t][c] - mx);
    mxv[c] = mx;
    inv[c] = 1.f / ssum;
  }
  __syncthreads();
  for (int idx = tid; idx < TT * CC; idx += 256) {
    const int t = idx >> 5;
    const int c = idx & 31;
    att_g[((size_t)bl * TT + t) * CC + c] = __expf(S[t][c] - mxv[c]) * inv[c];
  }
}

// ---------------------------------------------------------------------------
// K3: memory read + residual. grid (96, 8): each block = 128-d slice, ALL 32
// channels (kills R5's 4x redundant xh read). 256 threads = 128 d x 2 t-halves.
// Accumulate S_f[c] = sum_t att[t][c] * x_f[t,d]  (3 fma/c/t, no Wc in loop;
// sum_t att = 1 absorbs bc). Epilogue: Wc-combine, fold halves via padded LDS,
// + residual q, coalesced store.
// ---------------------------------------------------------------------------
__global__ __launch_bounds__(256, 3) void k_out(const float* __restrict__ xl,
                                                const float* __restrict__ xh,
                                                const float* __restrict__ att_g,
                                                const float* __restrict__ Wq,
                                                const float* __restrict__ bq,
                                                const float* __restrict__ Wc,
                                                const float* __restrict__ bc,
                                                float* __restrict__ out) {
  __shared__ __align__(16) float att[TT * CC];   // 4.6 KB
  __shared__ float red[128 * 33];                // 16.9 KB, pad 33: conflict-free
  const int bl = blockIdx.x;
  const int b = bl / LL, l = bl % LL;
  const int dh = blockIdx.y;             // 0..7
  const int tid = threadIdx.x;
  const int dl = tid & 127, th = tid >> 7;

  {
    const float4* src = (const float4*)(att_g + (size_t)bl * TT * CC);
    float4* dst = (float4*)att;
    for (int i = tid; i < TT * CC / 4; i += 256) dst[i] = src[i];
  }
  __syncthreads();

  const int d = dh * 128 + dl;
  float S0[CC], S1[CC], S2[CC];
  #pragma unroll
  for (int c = 0; c < CC; ++c) { S0[c] = 0.f; S1[c] = 0.f; S2[c] = 0.f; }

  const float* ph = xh + (((size_t)bl * TT + th * 18) * DD + d) * 3;
  #pragma unroll 3
  for (int tt = 0; tt < 18; ++tt) {
    const int t = th * 18 + tt;
    const float x0 = ph[0], x1 = ph[1], x2 = ph[2];
    ph += DD * 3;
    const float4* arow = (const float4*)&att[t * CC];
    #pragma unroll
    for (int cq = 0; cq < 8; ++cq) {
      const float4 a = arow[cq];         // LDS broadcast
      const int c = cq * 4;
      S0[c+0] = fmaf(a.x, x0, S0[c+0]); S1[c+0] = fmaf(a.x, x1, S1[c+0]); S2[c+0] = fmaf(a.x, x2, S2[c+0]);
      S0[c+1] = fmaf(a.y, x0, S0[c+1]); S1[c+1] = fmaf(a.y, x1, S1[c+1]); S2[c+1] = fmaf(a.y, x2, S2[c+1]);
      S0[c+2] = fmaf(a.z, x0, S0[c+2]); S1[c+2] = fmaf(a.z, x1, S1[c+2]); S2[c+2] = fmaf(a.z, x2, S2[c+2]);
      S0[c+3] = fmaf(a.w, x0, S0[c+3]); S1[c+3] = fmaf(a.w, x1, S1[c+3]); S2[c+3] = fmaf(a.w, x2, S2[c+3]);
    }
  }

  // Wc-combine (wave-uniform scalar loads).
  float o[CC];
  #pragma unroll
  for (int c = 0; c < CC; ++c)
    o[c] = fmaf(Wc[c*3], S0[c], fmaf(Wc[c*3+1], S1[c], Wc[c*3+2] * S2[c]));

  if (th == 1) {
    #pragma unroll
    for (int c = 0; c < CC; ++c) red[dl * 33 + c] = o[c];
  }
  __syncthreads();
  if (th == 0) {
    const float y0 = xl[((size_t)bl * DD + d) * 3 + 0];
    const float y1 = xl[((size_t)bl * DD + d) * 3 + 1];
    const float y2 = xl[((size_t)bl * DD + d) * 3 + 2];
    #pragma unroll
    for (int c = 0; c < CC; ++c) {
      const float qv = fmaf(Wq[c*3], y0, fmaf(Wq[c*3+1], y1, fmaf(Wq[c*3+2], y2, bq[c])));
      out[(((size_t)b * CC + c) * LL + l) * DD + d] = (o[c] + red[dl * 33 + c]) + (qv + bc[c]);
    }
  }
}

// ---------------------------------------------------------------------------
extern "C" void kernel_launch(void* const* d_in, const int* in_sizes, int n_in,
                              void* d_out, int out_size, void* d_ws, size_t ws_size,
                              hipStream_t stream) {
  const float* xl = (const float*)d_in[0];  // (B,L,D,F)
  const float* xh = (const float*)d_in[1];  // (B,L,T,D,F)
  const float* Wq = (const float*)d_in[2];
  const float* bq = (const float*)d_in[3];
  const float* Wm = (const float*)d_in[4];
  const float* bm = (const float*)d_in[5];
  const float* Wc = (const float*)d_in[6];
  const float* bc = (const float*)d_in[7];
  float* out = (float*)d_out;               // (B,C,L,D)

  float* mqp   = (float*)d_ws;                               // [bl][t][8][c], 3.5 MB
  float* att_g = mqp + (size_t)BB * LL * TT * NDC * CC;      // [bl][t][c], 0.44 MB

  k_mq  <<<dim3(BB * LL, NDC), 256, 0, stream>>>(xl, xh, Wm, bm, Wq, bq, mqp);
  k_soft<<<dim3(BB * LL),      256, 0, stream>>>(mqp, att_g);
  k_out <<<dim3(BB * LL, NDC), 256, 0, stream>>>(xl, xh, att_g, Wq, bq, Wc, bc, out);
}

// Round 7
// 158.422 us; speedup vs baseline: 2.7377x; 2.7377x over previous
//
#include <hip/hip_runtime.h>
#include <math.h>

// Problem constants (fixed by the reference).
#define BB 8
#define LL 12
#define TT 36
#define DD 1024
#define FF 3
#define CC 32
#define NDC 8               // 128-d slices in k_mq / k_out

// ---------------------------------------------------------------------------
// K1: partial scores. grid (96,8) = 768 blocks (3/CU, 12 waves/CU).
// R4's proven mapping: 256 thr = (c=32) x (s=8, 16 d each); q[16] in regs.
// NEW: explicit 2-deep register double-buffer over t (xa/xb = 12 float4 each)
// so ~24 loads stay in flight per wave -- R4 stalled each t on a 12-load
// batch; R5 starved it to 28 VGPRs; R6 spilled. Target ~140 VGPR, no cap.
// ---------------------------------------------------------------------------
__global__ __launch_bounds__(256) void k_mq(const float* __restrict__ xl,
                                            const float* __restrict__ xh,
                                            const float* __restrict__ Wm,
                                            const float* __restrict__ bm,
                                            const float* __restrict__ Wq,
                                            const float* __restrict__ bq,
                                            float* __restrict__ mqp) {
  __shared__ float part[TT][8][CC];     // 36 KB
  const int bl = blockIdx.x;            // 0..95
  const int dc = blockIdx.y;            // 0..7 (128-d chunk)
  const int tid = threadIdx.x;
  const int c  = tid & 31;
  const int s  = tid >> 5;              // 0..7 (16-d sub)
  const int d0 = dc * 128 + s * 16;

  // q[c, d0..d0+15] in registers.
  const float wq0 = Wq[c * 3 + 0], wq1 = Wq[c * 3 + 1], wq2 = Wq[c * 3 + 2];
  const float bq0 = bq[c];
  float q[16];
  {
    const float4* xlr = (const float4*)(xl + ((size_t)bl * DD + d0) * 3);
    float4 xb4[12];
    #pragma unroll
    for (int i = 0; i < 12; ++i) xb4[i] = xlr[i];
    const float* x = (const float*)xb4;
    #pragma unroll
    for (int k = 0; k < 16; ++k)
      q[k] = fmaf(wq0, x[k * 3 + 0], fmaf(wq1, x[k * 3 + 1], fmaf(wq2, x[k * 3 + 2], bq0)));
  }

  const float w0 = Wm[c * 3 + 0], w1 = Wm[c * 3 + 1], w2 = Wm[c * 3 + 2];
  const float b0 = bm[c];

  const float4* const xh4 = (const float4*)(xh + ((size_t)bl * TT * DD + d0) * 3);
  // t-row stride in float4s: DD*3/4 = 768.

  float4 xa[12], xb[12];

  auto load12 = [&](float4* buf, int t) {
    const float4* p = xh4 + (size_t)t * 768;
    #pragma unroll
    for (int i = 0; i < 12; ++i) buf[i] = p[i];
  };
  auto consume = [&](const float4* buf, int t) {
    const float* x = (const float*)buf;
    float a0 = 0.f, a1 = 0.f, a2 = 0.f, a3 = 0.f;
    #pragma unroll
    for (int k = 0; k < 16; k += 4) {
      a0 = fmaf(fmaf(w0, x[(k+0)*3], fmaf(w1, x[(k+0)*3+1], fmaf(w2, x[(k+0)*3+2], b0))), q[k+0], a0);
      a1 = fmaf(fmaf(w0, x[(k+1)*3], fmaf(w1, x[(k+1)*3+1], fmaf(w2, x[(k+1)*3+2], b0))), q[k+1], a1);
      a2 = fmaf(fmaf(w0, x[(k+2)*3], fmaf(w1, x[(k+2)*3+1], fmaf(w2, x[(k+2)*3+2], b0))), q[k+2], a2);
      a3 = fmaf(fmaf(w0, x[(k+3)*3], fmaf(w1, x[(k+3)*3+1], fmaf(w2, x[(k+3)*3+2], b0))), q[k+3], a3);
    }
    part[t][s][c] = (a0 + a1) + (a2 + a3);
  };

  load12(xa, 0);
  load12(xb, 1);
  #pragma unroll 2
  for (int tt = 0; tt < TT; tt += 2) {
    consume(xa, tt);
    if (tt + 2 < TT) load12(xa, tt + 2);
    consume(xb, tt + 1);
    if (tt + 3 < TT) load12(xb, tt + 3);
  }
  __syncthreads();

  // Block reduction over s: 1152 outputs across 256 threads.
  for (int idx = tid; idx < TT * CC; idx += 256) {
    const int t  = idx >> 5;
    const int cc = idx & 31;
    float v = 0.f;
    #pragma unroll
    for (int j = 0; j < 8; ++j) v += part[t][j][cc];
    mqp[(((size_t)bl * TT + t) * NDC + dc) * CC + cc] = v;
  }
}

// ---------------------------------------------------------------------------
// K2: reduce mqp over dc, relu+softmax over t, write att[bl][t][c]. grid(96).
// ---------------------------------------------------------------------------
__global__ __launch_bounds__(256) void k_soft(const float* __restrict__ mqp,
                                              float* __restrict__ att_g) {
  __shared__ float S[TT][CC];
  __shared__ float mxv[CC], inv[CC];
  const int bl = blockIdx.x;
  const int tid = threadIdx.x;

  for (int idx = tid; idx < TT * CC; idx += 256) {
    const int t = idx >> 5;
    const int c = idx & 31;
    const float* p = mqp + (((size_t)bl * TT + t) * NDC) * CC + c;
    float v = 0.f;
    #pragma unroll
    for (int j = 0; j < NDC; ++j) v += p[j * CC];
    S[t][c] = fmaxf(v, 0.f);
  }
  __syncthreads();
  if (tid < CC) {
    const int c = tid;
    float mx = 0.f;                     // relu >= 0 -> valid seed
    #pragma unroll
    for (int t = 0; t < TT; ++t) mx = fmaxf(mx, S[t][c]);
    float ssum = 0.f;
    #pragma unroll
    for (int t = 0; t < TT; ++t) ssum += __expf(S[t][c] - mx);
    mxv[c] = mx;
    inv[c] = 1.f / ssum;
  }
  __syncthreads();
  for (int idx = tid; idx < TT * CC; idx += 256) {
    const int t = idx >> 5;
    const int c = idx & 31;
    att_g[((size_t)bl * TT + t) * CC + c] = __expf(S[t][c] - mxv[c]) * inv[c];
  }
}

// ---------------------------------------------------------------------------
// K3: memory read + residual. grid (96,8): block = 128-d slice, all 32 ch.
// 256 thr = 128 d-lanes x 2 CHANNEL halves (16 c each) -- no cross-thread
// reduction, 48 accumulators/thread (R6's 128-acc version spilled).
// S_f[c] = sum_t att[t][c]*x_f[t,d]; Wc/bc/q folded in epilogue (sum att = 1
// absorbs bc). 4-deep rolling prefetch of the 3 xh scalars per t.
// ---------------------------------------------------------------------------
__global__ __launch_bounds__(256) void k_out(const float* __restrict__ xl,
                                             const float* __restrict__ xh,
                                             const float* __restrict__ att_g,
                                             const float* __restrict__ Wq,
                                             const float* __restrict__ bq,
                                             const float* __restrict__ Wc,
                                             const float* __restrict__ bc,
                                             float* __restrict__ out) {
  __shared__ __align__(16) float att[TT * CC];   // 4.6 KB
  const int bl = blockIdx.x;
  const int b = bl / LL, l = bl % LL;
  const int dh = blockIdx.y;            // 0..7
  const int tid = threadIdx.x;
  const int dl = tid & 127;
  const int ch = tid >> 7;              // 0..1 (16-channel half)

  {
    const float4* src = (const float4*)(att_g + (size_t)bl * TT * CC);
    float4* dst = (float4*)att;
    for (int i = tid; i < TT * CC / 4; i += 256) dst[i] = src[i];
  }
  __syncthreads();

  const int d = dh * 128 + dl;
  const int c0 = ch * 16;

  float S0[16], S1[16], S2[16];
  #pragma unroll
  for (int u = 0; u < 16; ++u) { S0[u] = 0.f; S1[u] = 0.f; S2[u] = 0.f; }

  const float* bp = xh + ((size_t)bl * TT * DD + d) * 3;  // + t*DD*3 per t
  float xq[4][3];
  #pragma unroll
  for (int j = 0; j < 4; ++j) {
    const float* p = bp + (size_t)j * DD * 3;
    xq[j][0] = p[0]; xq[j][1] = p[1]; xq[j][2] = p[2];
  }

  #pragma unroll 4
  for (int t = 0; t < TT; ++t) {
    const int sl = t & 3;
    const float x0 = xq[sl][0], x1 = xq[sl][1], x2 = xq[sl][2];
    if (t + 4 < TT) {                   // rolling prefetch, 4 t ahead
      const float* p = bp + (size_t)(t + 4) * DD * 3;
      xq[sl][0] = p[0]; xq[sl][1] = p[1]; xq[sl][2] = p[2];
    }
    const float4* arow = (const float4*)&att[t * CC + c0];
    #pragma unroll
    for (int cq = 0; cq < 4; ++cq) {
      const float4 a = arow[cq];        // LDS broadcast (wave-uniform addr)
      const int u = cq * 4;
      S0[u+0] = fmaf(a.x, x0, S0[u+0]); S1[u+0] = fmaf(a.x, x1, S1[u+0]); S2[u+0] = fmaf(a.x, x2, S2[u+0]);
      S0[u+1] = fmaf(a.y, x0, S0[u+1]); S1[u+1] = fmaf(a.y, x1, S1[u+1]); S2[u+1] = fmaf(a.y, x2, S2[u+1]);
      S0[u+2] = fmaf(a.z, x0, S0[u+2]); S1[u+2] = fmaf(a.z, x1, S1[u+2]); S2[u+2] = fmaf(a.z, x2, S2[u+2]);
      S0[u+3] = fmaf(a.w, x0, S0[u+3]); S1[u+3] = fmaf(a.w, x1, S1[u+3]); S2[u+3] = fmaf(a.w, x2, S2[u+3]);
    }
  }

  // Epilogue: Wc-combine (+bc), residual q, coalesced stores (64 consec d/wave).
  const float y0 = xl[((size_t)bl * DD + d) * 3 + 0];
  const float y1 = xl[((size_t)bl * DD + d) * 3 + 1];
  const float y2 = xl[((size_t)bl * DD + d) * 3 + 2];
  #pragma unroll
  for (int u = 0; u < 16; ++u) {
    const int c = c0 + u;
    const float o  = fmaf(Wc[c*3], S0[u], fmaf(Wc[c*3+1], S1[u], fmaf(Wc[c*3+2], S2[u], bc[c])));
    const float qv = fmaf(Wq[c*3], y0,    fmaf(Wq[c*3+1], y1,    fmaf(Wq[c*3+2], y2, bq[c])));
    out[(((size_t)b * CC + c) * LL + l) * DD + d] = qv + o;
  }
}

// ---------------------------------------------------------------------------
extern "C" void kernel_launch(void* const* d_in, const int* in_sizes, int n_in,
                              void* d_out, int out_size, void* d_ws, size_t ws_size,
                              hipStream_t stream) {
  const float* xl = (const float*)d_in[0];  // (B,L,D,F)
  const float* xh = (const float*)d_in[1];  // (B,L,T,D,F)
  const float* Wq = (const float*)d_in[2];
  const float* bq = (const float*)d_in[3];
  const float* Wm = (const float*)d_in[4];
  const float* bm = (const float*)d_in[5];
  const float* Wc = (const float*)d_in[6];
  const float* bc = (const float*)d_in[7];
  float* out = (float*)d_out;               // (B,C,L,D)

  float* mqp   = (float*)d_ws;                               // [bl][t][8][c], 3.5 MB
  float* att_g = mqp + (size_t)BB * LL * TT * NDC * CC;      // [bl][t][c], 0.44 MB

  k_mq  <<<dim3(BB * LL, NDC), 256, 0, stream>>>(xl, xh, Wm, bm, Wq, bq, mqp);
  k_soft<<<dim3(BB * LL),      256, 0, stream>>>(mqp, att_g);
  k_out <<<dim3(BB * LL, NDC), 256, 0, stream>>>(xl, xh, att_g, Wq, bq, Wc, bc, out);
}

// Round 8
// 137.135 us; speedup vs baseline: 3.1626x; 1.1552x over previous
//
#include <hip/hip_runtime.h>
#include <math.h>

// Problem constants (fixed by the reference).
#define BB 8
#define LL 12
#define TT 36
#define DD 1024
#define CC 32

// ---------------------------------------------------------------------------
// K1: Z[t,f,g] = sum_d xh[t,d,f]*xl[d,g]  (9) and H[t,f] = sum_d xh[t,d,f] (3)
// per (bl,t). One wave per block, 3456 blocks (~13.5 waves/CU).
// Lane owns d = lane*16..+15: 12 float4 xh + 12 float4 xl, ALL DISTINCT and
// sequence-covering (fixes the R4-R7 broadcast-address TA wall).
// 12-value wave shuffle reduction; lane 0 stores 48 B.
// ---------------------------------------------------------------------------
__global__ __launch_bounds__(64) void k_Z(const float* __restrict__ xl,
                                          const float* __restrict__ xh,
                                          float* __restrict__ Zg) {
  const int blk  = blockIdx.x;          // bl*TT + t
  const int bl   = blk / TT;
  const int lane = threadIdx.x;         // 0..63
  const float4* xh4 = (const float4*)xh + (size_t)blk * 768 + lane * 12;
  const float4* xl4 = (const float4*)xl + (size_t)bl  * 768 + lane * 12;

  float Z00=0,Z01=0,Z02=0,Z10=0,Z11=0,Z12=0,Z20=0,Z21=0,Z22=0;
  float H0=0,H1=0,H2=0;
  #pragma unroll
  for (int h = 0; h < 2; ++h) {         // two halves of 8 d (register budget)
    float4 a4[6], b4[6];
    #pragma unroll
    for (int i = 0; i < 6; ++i) a4[i] = xh4[h*6 + i];
    #pragma unroll
    for (int i = 0; i < 6; ++i) b4[i] = xl4[h*6 + i];
    const float* a = (const float*)a4;
    const float* b = (const float*)b4;
    #pragma unroll
    for (int k = 0; k < 8; ++k) {
      const float x0=a[k*3], x1=a[k*3+1], x2=a[k*3+2];
      const float y0=b[k*3], y1=b[k*3+1], y2=b[k*3+2];
      Z00 = fmaf(x0,y0,Z00); Z01 = fmaf(x0,y1,Z01); Z02 = fmaf(x0,y2,Z02);
      Z10 = fmaf(x1,y0,Z10); Z11 = fmaf(x1,y1,Z11); Z12 = fmaf(x1,y2,Z12);
      Z20 = fmaf(x2,y0,Z20); Z21 = fmaf(x2,y1,Z21); Z22 = fmaf(x2,y2,Z22);
      H0 += x0; H1 += x1; H2 += x2;
    }
  }

  float v[12] = {Z00,Z01,Z02,Z10,Z11,Z12,Z20,Z21,Z22,H0,H1,H2};
  #pragma unroll
  for (int off = 32; off > 0; off >>= 1)
    #pragma unroll
    for (int j = 0; j < 12; ++j) v[j] += __shfl_down(v[j], off);

  if (lane == 0) {
    float4* o = (float4*)(Zg + (size_t)blk * 16);
    o[0] = make_float4(v[0], v[1], v[2],  v[3]);
    o[1] = make_float4(v[4], v[5], v[6],  v[7]);
    o[2] = make_float4(v[8], v[9], v[10], v[11]);
  }
}

// ---------------------------------------------------------------------------
// K2: assemble mq from Z/H, relu+softmax over t, write att[bl][t][c].
// grid (96), 256 threads. mq[c,t] = sum_fg Wm[c,f]Wq[c,g] Z[t,f,g]
//   + bq[c] * sum_f Wm[c,f] H[t,f] + bm[c]*(Wq[c]·XLs + 1024*bq[c]).
// XLs[g] = sum_d xl[d,g] computed in-block (12 floats/thread + shuffle).
// ---------------------------------------------------------------------------
__global__ __launch_bounds__(256) void k_soft(const float* __restrict__ xl,
                                              const float* __restrict__ Zg,
                                              const float* __restrict__ Wm,
                                              const float* __restrict__ bm,
                                              const float* __restrict__ Wq,
                                              const float* __restrict__ bq,
                                              float* __restrict__ att_g) {
  __shared__ __align__(16) float ZS[TT * 16];
  __shared__ float S[TT][CC];
  __shared__ float xlp[4][3];
  __shared__ float mxv[CC], inv[CC];
  const int bl = blockIdx.x;
  const int tid = threadIdx.x;

  {                                     // stage Z/H rows
    const float4* src = (const float4*)(Zg + (size_t)bl * TT * 16);
    float4* dst = (float4*)ZS;
    if (tid < TT * 4) dst[tid] = src[tid];
  }
  {                                     // XLs partials: 12 floats per thread
    const float4* x4 = (const float4*)xl + (size_t)bl * 768 + tid * 3;
    const float4 a = x4[0], b = x4[1], c4 = x4[2];
    float s0 = a.x + a.w + b.z + c4.y;  // g=0 phases of e=12*tid..+11
    float s1 = a.y + b.x + b.w + c4.z;  // g=1
    float s2 = a.z + b.y + c4.x + c4.w; // g=2
    #pragma unroll
    for (int off = 32; off > 0; off >>= 1) {
      s0 += __shfl_down(s0, off);
      s1 += __shfl_down(s1, off);
      s2 += __shfl_down(s2, off);
    }
    if ((tid & 63) == 0) {
      const int w = tid >> 6;
      xlp[w][0] = s0; xlp[w][1] = s1; xlp[w][2] = s2;
    }
  }
  __syncthreads();

  const float XL0 = (xlp[0][0]+xlp[1][0]) + (xlp[2][0]+xlp[3][0]);
  const float XL1 = (xlp[0][1]+xlp[1][1]) + (xlp[2][1]+xlp[3][1]);
  const float XL2 = (xlp[0][2]+xlp[1][2]) + (xlp[2][2]+xlp[3][2]);

  const int c = tid & 31;
  const float wm0 = Wm[c*3], wm1 = Wm[c*3+1], wm2 = Wm[c*3+2];
  const float wq0 = Wq[c*3], wq1 = Wq[c*3+1], wq2 = Wq[c*3+2];
  const float bqv = bq[c], bmv = bm[c];
  const float K = bmv * (fmaf(wq0, XL0, fmaf(wq1, XL1, wq2 * XL2)) + 1024.f * bqv);

  for (int idx = tid; idx < TT * CC; idx += 256) {
    const int t = idx >> 5;
    const float* z = &ZS[t * 16];       // 32 lanes same t -> LDS broadcast
    float m = K;
    m = fmaf(wm0, fmaf(wq0, z[0], fmaf(wq1, z[1], fmaf(wq2, z[2], bqv * z[9]))),  m);
    m = fmaf(wm1, fmaf(wq0, z[3], fmaf(wq1, z[4], fmaf(wq2, z[5], bqv * z[10]))), m);
    m = fmaf(wm2, fmaf(wq0, z[6], fmaf(wq1, z[7], fmaf(wq2, z[8], bqv * z[11]))), m);
    S[t][c] = fmaxf(m, 0.f);            // relu
  }
  __syncthreads();

  if (tid < CC) {
    float mx = 0.f;                     // relu >= 0 -> valid seed
    #pragma unroll
    for (int t = 0; t < TT; ++t) mx = fmaxf(mx, S[t][tid]);
    float ssum = 0.f;
    #pragma unroll
    for (int t = 0; t < TT; ++t) ssum += __expf(S[t][tid] - mx);
    mxv[tid] = mx;
    inv[tid] = 1.f / ssum;
  }
  __syncthreads();

  for (int idx = tid; idx < TT * CC; idx += 256) {
    const int t = idx >> 5;
    att_g[((size_t)bl * TT + t) * CC + c] = __expf(S[t][c] - mxv[c]) * inv[c];
  }
}

// ---------------------------------------------------------------------------
// K3: o = att(32x36) . c(36 x 3072) + q, per bl. grid (96,4), 256 thr.
// Wave = 64 lanes x distinct 4-d groups (3 float4/t, fully coalesced);
// wave index = 8-channel group. 32 accumulators/thread, no cross-thread
// reduction. bc folded out (sum_t att = 1); Wc applied in-loop (2 FMA + mul),
// q-residual in epilogue; float4 stores (1KB/wave-instr).
// ---------------------------------------------------------------------------
__global__ __launch_bounds__(256) void k_out(const float* __restrict__ xl,
                                             const float* __restrict__ xh,
                                             const float* __restrict__ att_g,
                                             const float* __restrict__ Wq,
                                             const float* __restrict__ bq,
                                             const float* __restrict__ Wc,
                                             const float* __restrict__ bc,
                                             float* __restrict__ out) {
  __shared__ __align__(16) float att[TT * CC];   // 4.6 KB
  const int bl = blockIdx.x;
  const int b = bl / LL, l = bl % LL;
  const int dh = blockIdx.y;            // 0..3 (256-d slice)
  const int tid = threadIdx.x;
  const int lane = tid & 63;
  const int cg = tid >> 6;              // 0..3 -> 8 channels
  const int c0 = cg * 8;
  const int dg = dh * 64 + lane;        // 4-d group index (0..255)

  {
    const float4* src = (const float4*)(att_g + (size_t)bl * TT * CC);
    float4* dst = (float4*)att;
    for (int i = tid; i < TT * CC / 4; i += 256) dst[i] = src[i];
  }
  __syncthreads();

  float wc[8][3];
  #pragma unroll
  for (int u = 0; u < 8; ++u) {
    const int c = c0 + u;
    wc[u][0] = Wc[c*3]; wc[u][1] = Wc[c*3+1]; wc[u][2] = Wc[c*3+2];
  }
  float acc[8][4];
  #pragma unroll
  for (int u = 0; u < 8; ++u)
    #pragma unroll
    for (int dd = 0; dd < 4; ++dd) acc[u][dd] = 0.f;

  const float4* base = (const float4*)xh + (size_t)bl * TT * 768 + dg * 3;
  float4 buf[2][3];
  #pragma unroll
  for (int i = 0; i < 3; ++i) buf[0][i] = base[i];
  #pragma unroll
  for (int i = 0; i < 3; ++i) buf[1][i] = base[768 + i];

  #pragma unroll 2
  for (int t = 0; t < TT; ++t) {
    float xv[12];
    {
      const float* x = (const float*)buf[t & 1];
      #pragma unroll
      for (int i = 0; i < 12; ++i) xv[i] = x[i];
    }
    if (t + 2 < TT) {                   // 2-deep rolling prefetch
      const float4* p = base + (size_t)(t + 2) * 768;
      #pragma unroll
      for (int i = 0; i < 3; ++i) buf[t & 1][i] = p[i];
    }
    const float4 a0 = *(const float4*)&att[t * CC + c0];
    const float4 a1 = *(const float4*)&att[t * CC + c0 + 4];
    const float av[8] = {a0.x,a0.y,a0.z,a0.w,a1.x,a1.y,a1.z,a1.w};
    #pragma unroll
    for (int u = 0; u < 8; ++u)
      #pragma unroll
      for (int dd = 0; dd < 4; ++dd) {
        const float m = fmaf(wc[u][0], xv[dd*3],
                        fmaf(wc[u][1], xv[dd*3+1], wc[u][2] * xv[dd*3+2]));
        acc[u][dd] = fmaf(av[u], m, acc[u][dd]);
      }
  }

  // Epilogue: + bc (sum att = 1) + residual q; float4 stores.
  float4 ql[3];
  {
    const float4* xl4 = (const float4*)xl + (size_t)bl * 768 + dg * 3;
    #pragma unroll
    for (int i = 0; i < 3; ++i) ql[i] = xl4[i];
  }
  const float* y = (const float*)ql;    // 12 floats = 4 d x 3 f
  #pragma unroll
  for (int u = 0; u < 8; ++u) {
    const int c = c0 + u;
    const float w0 = Wq[c*3], w1 = Wq[c*3+1], w2 = Wq[c*3+2];
    const float b0 = bq[c], bcv = bc[c];
    float4 o;
    o.x = acc[u][0] + bcv + fmaf(w0, y[0], fmaf(w1, y[1],  fmaf(w2, y[2],  b0)));
    o.y = acc[u][1] + bcv + fmaf(w0, y[3], fmaf(w1, y[4],  fmaf(w2, y[5],  b0)));
    o.z = acc[u][2] + bcv + fmaf(w0, y[6], fmaf(w1, y[7],  fmaf(w2, y[8],  b0)));
    o.w = acc[u][3] + bcv + fmaf(w0, y[9], fmaf(w1, y[10], fmaf(w2, y[11], b0)));
    *(float4*)(out + (((size_t)b * CC + c) * LL + l) * DD + dg * 4) = o;
  }
}

// ---------------------------------------------------------------------------
extern "C" void kernel_launch(void* const* d_in, const int* in_sizes, int n_in,
                              void* d_out, int out_size, void* d_ws, size_t ws_size,
                              hipStream_t stream) {
  const float* xl = (const float*)d_in[0];  // (B,L,D,F)
  const float* xh = (const float*)d_in[1];  // (B,L,T,D,F)
  const float* Wq = (const float*)d_in[2];
  const float* bq = (const float*)d_in[3];
  const float* Wm = (const float*)d_in[4];
  const float* bm = (const float*)d_in[5];
  const float* Wc = (const float*)d_in[6];
  const float* bc = (const float*)d_in[7];
  float* out = (float*)d_out;               // (B,C,L,D)

  float* Zg    = (float*)d_ws;                          // [bl*T][16], 221 KB
  float* att_g = Zg + (size_t)BB * LL * TT * 16;        // [bl][t][c], 442 KB

  k_Z   <<<dim3(BB * LL * TT), 64,  0, stream>>>(xl, xh, Zg);
  k_soft<<<dim3(BB * LL),      256, 0, stream>>>(xl, Zg, Wm, bm, Wq, bq, att_g);
  k_out <<<dim3(BB * LL, 4),   256, 0, stream>>>(xl, xh, att_g, Wq, bq, Wc, bc, out);
}

// Round 9
// 134.177 us; speedup vs baseline: 3.2324x; 1.0220x over previous
//
#include <hip/hip_runtime.h>
#include <math.h>

// Problem constants (fixed by the reference).
#define BB 8
#define LL 12
#define TT 36
#define DD 1024
#define CC 32

// ---------------------------------------------------------------------------
// K1: Z[t,f,g] = sum_d xh[t,d,f]*xl[d,g] (9) and H[t,f] = sum_d xh[t,d,f] (3)
// per (bl,t). One wave per block, 3456 blocks. Lane owns 16 d: 24 float4
// loads issued as ONE batch (R8 split them into 2 dependent halves; at 1
// wave/block there are ~500 VGPRs to burn -- use them for MLP).
// 12-value wave shuffle reduction; lane 0 stores 48 B.
// ---------------------------------------------------------------------------
__global__ __launch_bounds__(64) void k_Z(const float* __restrict__ xl,
                                          const float* __restrict__ xh,
                                          float* __restrict__ Zg) {
  const int blk  = blockIdx.x;          // bl*TT + t
  const int bl   = blk / TT;
  const int lane = threadIdx.x;         // 0..63
  const float4* xh4 = (const float4*)xh + (size_t)blk * 768 + lane * 12;
  const float4* xl4 = (const float4*)xl + (size_t)bl  * 768 + lane * 12;

  float4 a4[12], b4[12];                // 24 loads in flight together
  #pragma unroll
  for (int i = 0; i < 12; ++i) a4[i] = xh4[i];
  #pragma unroll
  for (int i = 0; i < 12; ++i) b4[i] = xl4[i];

  float Z00=0,Z01=0,Z02=0,Z10=0,Z11=0,Z12=0,Z20=0,Z21=0,Z22=0;
  float H0=0,H1=0,H2=0;
  const float* a = (const float*)a4;
  const float* b = (const float*)b4;
  #pragma unroll
  for (int k = 0; k < 16; ++k) {
    const float x0=a[k*3], x1=a[k*3+1], x2=a[k*3+2];
    const float y0=b[k*3], y1=b[k*3+1], y2=b[k*3+2];
    Z00 = fmaf(x0,y0,Z00); Z01 = fmaf(x0,y1,Z01); Z02 = fmaf(x0,y2,Z02);
    Z10 = fmaf(x1,y0,Z10); Z11 = fmaf(x1,y1,Z11); Z12 = fmaf(x1,y2,Z12);
    Z20 = fmaf(x2,y0,Z20); Z21 = fmaf(x2,y1,Z21); Z22 = fmaf(x2,y2,Z22);
    H0 += x0; H1 += x1; H2 += x2;
  }

  float v[12] = {Z00,Z01,Z02,Z10,Z11,Z12,Z20,Z21,Z22,H0,H1,H2};
  #pragma unroll
  for (int off = 32; off > 0; off >>= 1)
    #pragma unroll
    for (int j = 0; j < 12; ++j) v[j] += __shfl_down(v[j], off);

  if (lane == 0) {
    float4* o = (float4*)(Zg + (size_t)blk * 16);
    o[0] = make_float4(v[0], v[1], v[2],  v[3]);
    o[1] = make_float4(v[4], v[5], v[6],  v[7]);
    o[2] = make_float4(v[8], v[9], v[10], v[11]);
  }
}

// ---------------------------------------------------------------------------
// K2: assemble mq from Z/H, relu+softmax over t, then emit
// P[bl][t][f][c] = att[t][c] * Wc[c][f]   (att (x) Wc precombined so k_out's
// inner loop is 3 fma per (c,d,t) instead of 4 instr). grid (96).
// ---------------------------------------------------------------------------
__global__ __launch_bounds__(256) void k_soft(const float* __restrict__ xl,
                                              const float* __restrict__ Zg,
                                              const float* __restrict__ Wm,
                                              const float* __restrict__ bm,
                                              const float* __restrict__ Wq,
                                              const float* __restrict__ bq,
                                              const float* __restrict__ Wc,
                                              float* __restrict__ Pg) {
  __shared__ __align__(16) float ZS[TT * 16];
  __shared__ float S[TT][CC];
  __shared__ float xlp[4][3];
  __shared__ float mxv[CC], inv[CC];
  const int bl = blockIdx.x;
  const int tid = threadIdx.x;

  {                                     // stage Z/H rows
    const float4* src = (const float4*)(Zg + (size_t)bl * TT * 16);
    float4* dst = (float4*)ZS;
    if (tid < TT * 4) dst[tid] = src[tid];
  }
  {                                     // XLs[g] = sum_d xl[d,g] partials
    const float4* x4 = (const float4*)xl + (size_t)bl * 768 + tid * 3;
    const float4 a = x4[0], b = x4[1], c4 = x4[2];
    float s0 = a.x + a.w + b.z + c4.y;
    float s1 = a.y + b.x + b.w + c4.z;
    float s2 = a.z + b.y + c4.x + c4.w;
    #pragma unroll
    for (int off = 32; off > 0; off >>= 1) {
      s0 += __shfl_down(s0, off);
      s1 += __shfl_down(s1, off);
      s2 += __shfl_down(s2, off);
    }
    if ((tid & 63) == 0) {
      const int w = tid >> 6;
      xlp[w][0] = s0; xlp[w][1] = s1; xlp[w][2] = s2;
    }
  }
  __syncthreads();

  const float XL0 = (xlp[0][0]+xlp[1][0]) + (xlp[2][0]+xlp[3][0]);
  const float XL1 = (xlp[0][1]+xlp[1][1]) + (xlp[2][1]+xlp[3][1]);
  const float XL2 = (xlp[0][2]+xlp[1][2]) + (xlp[2][2]+xlp[3][2]);

  const int c = tid & 31;
  const float wm0 = Wm[c*3], wm1 = Wm[c*3+1], wm2 = Wm[c*3+2];
  const float wq0 = Wq[c*3], wq1 = Wq[c*3+1], wq2 = Wq[c*3+2];
  const float bqv = bq[c], bmv = bm[c];
  const float K = bmv * (fmaf(wq0, XL0, fmaf(wq1, XL1, wq2 * XL2)) + 1024.f * bqv);

  for (int idx = tid; idx < TT * CC; idx += 256) {
    const int t = idx >> 5;
    const float* z = &ZS[t * 16];
    float m = K;
    m = fmaf(wm0, fmaf(wq0, z[0], fmaf(wq1, z[1], fmaf(wq2, z[2], bqv * z[9]))),  m);
    m = fmaf(wm1, fmaf(wq0, z[3], fmaf(wq1, z[4], fmaf(wq2, z[5], bqv * z[10]))), m);
    m = fmaf(wm2, fmaf(wq0, z[6], fmaf(wq1, z[7], fmaf(wq2, z[8], bqv * z[11]))), m);
    S[t][c] = fmaxf(m, 0.f);            // relu
  }
  __syncthreads();

  if (tid < CC) {
    float mx = 0.f;                     // relu >= 0 -> valid seed
    #pragma unroll
    for (int t = 0; t < TT; ++t) mx = fmaxf(mx, S[t][tid]);
    float ssum = 0.f;
    #pragma unroll
    for (int t = 0; t < TT; ++t) ssum += __expf(S[t][tid] - mx);
    mxv[tid] = mx;
    inv[tid] = 1.f / ssum;
  }
  __syncthreads();

  const float wc0 = Wc[c*3], wc1 = Wc[c*3+1], wc2 = Wc[c*3+2];
  for (int idx = tid; idx < TT * CC; idx += 256) {
    const int t = idx >> 5;
    const float e = __expf(S[t][c] - mxv[c]) * inv[c];
    float* pp = Pg + (((size_t)bl * TT + t) * 3) * CC + c;
    pp[0]      = e * wc0;
    pp[CC]     = e * wc1;
    pp[2 * CC] = e * wc2;
  }
}

// ---------------------------------------------------------------------------
// K3: o[c,d] = sum_t sum_f P[t,f,c] * xh[t,d,f]; out = o + bc + q. Per bl.
// grid (96,4), 512 threads = 8 waves x 4 channels; lane owns a 4-d group
// (3 float4/t, fully coalesced, xh read ONCE). Ring-3 register prefetch.
// P staged in LDS (13.8 KB), read as wave-uniform float4 broadcasts.
// acc[4][4]=16 regs -- no spill. 12 waves/CU.
// ---------------------------------------------------------------------------
__global__ __launch_bounds__(512) void k_out(const float* __restrict__ xl,
                                             const float* __restrict__ xh,
                                             const float* __restrict__ Pg,
                                             const float* __restrict__ Wq,
                                             const float* __restrict__ bq,
                                             const float* __restrict__ bc,
                                             float* __restrict__ out) {
  __shared__ __align__(16) float4 PS[TT * 3 * 8];   // [t][f][cq], 13.8 KB
  const int bl = blockIdx.x;
  const int b = bl / LL, l = bl % LL;
  const int dh = blockIdx.y;            // 0..3 (256-d slice)
  const int tid = threadIdx.x;
  const int lane = tid & 63;
  const int cq = tid >> 6;              // 0..7 -> 4 channels
  const int c0 = cq * 4;
  const int dg = dh * 64 + lane;        // 4-d group index (0..255)

  {
    const float4* src = (const float4*)(Pg + (size_t)bl * TT * 3 * CC);
    for (int i = tid; i < TT * 3 * 8; i += 512) PS[i] = src[i];
  }
  __syncthreads();

  const float4* base = (const float4*)xh + (size_t)bl * TT * 768 + dg * 3;
  float4 buf[3][3];
  #pragma unroll
  for (int j = 0; j < 3; ++j)
    #pragma unroll
    for (int i = 0; i < 3; ++i) buf[j][i] = base[(size_t)j * 768 + i];

  float acc[4][4];
  #pragma unroll
  for (int u = 0; u < 4; ++u)
    #pragma unroll
    for (int dd = 0; dd < 4; ++dd) acc[u][dd] = 0.f;

  #pragma unroll
  for (int t = 0; t < TT; ++t) {
    const int sl = t % 3;               // compile-time (full unroll)
    float xv[12];
    {
      const float* x = (const float*)buf[sl];
      #pragma unroll
      for (int i = 0; i < 12; ++i) xv[i] = x[i];
    }
    if (t + 3 < TT) {                   // ring prefetch, 3 t ahead
      const float4* p = base + (size_t)(t + 3) * 768;
      #pragma unroll
      for (int i = 0; i < 3; ++i) buf[sl][i] = p[i];
    }
    const float4 P0 = PS[(t * 3 + 0) * 8 + cq];   // LDS broadcast
    const float4 P1 = PS[(t * 3 + 1) * 8 + cq];
    const float4 P2 = PS[(t * 3 + 2) * 8 + cq];
    const float p0[4] = {P0.x, P0.y, P0.z, P0.w};
    const float p1[4] = {P1.x, P1.y, P1.z, P1.w};
    const float p2[4] = {P2.x, P2.y, P2.z, P2.w};
    #pragma unroll
    for (int u = 0; u < 4; ++u)
      #pragma unroll
      for (int dd = 0; dd < 4; ++dd)
        acc[u][dd] = fmaf(p0[u], xv[dd*3],
                     fmaf(p1[u], xv[dd*3+1],
                     fmaf(p2[u], xv[dd*3+2], acc[u][dd])));
  }

  // Epilogue: + bc (sum att = 1) + residual q; float4 stores (1KB/wave).
  float4 ql[3];
  {
    const float4* xl4 = (const float4*)xl + (size_t)bl * 768 + dg * 3;
    #pragma unroll
    for (int i = 0; i < 3; ++i) ql[i] = xl4[i];
  }
  const float* y = (const float*)ql;    // 12 floats = 4 d x 3 f
  #pragma unroll
  for (int u = 0; u < 4; ++u) {
    const int c = c0 + u;
    const float w0 = Wq[c*3], w1 = Wq[c*3+1], w2 = Wq[c*3+2];
    const float b0 = bq[c], bcv = bc[c];
    float4 o;
    o.x = acc[u][0] + bcv + fmaf(w0, y[0], fmaf(w1, y[1],  fmaf(w2, y[2],  b0)));
    o.y = acc[u][1] + bcv + fmaf(w0, y[3], fmaf(w1, y[4],  fmaf(w2, y[5],  b0)));
    o.z = acc[u][2] + bcv + fmaf(w0, y[6], fmaf(w1, y[7],  fmaf(w2, y[8],  b0)));
    o.w = acc[u][3] + bcv + fmaf(w0, y[9], fmaf(w1, y[10], fmaf(w2, y[11], b0)));
    *(float4*)(out + (((size_t)b * CC + c) * LL + l) * DD + dg * 4) = o;
  }
}

// ---------------------------------------------------------------------------
extern "C" void kernel_launch(void* const* d_in, const int* in_sizes, int n_in,
                              void* d_out, int out_size, void* d_ws, size_t ws_size,
                              hipStream_t stream) {
  const float* xl = (const float*)d_in[0];  // (B,L,D,F)
  const float* xh = (const float*)d_in[1];  // (B,L,T,D,F)
  const float* Wq = (const float*)d_in[2];
  const float* bq = (const float*)d_in[3];
  const float* Wm = (const float*)d_in[4];
  const float* bm = (const float*)d_in[5];
  const float* Wc = (const float*)d_in[6];
  const float* bc = (const float*)d_in[7];
  float* out = (float*)d_out;               // (B,C,L,D)

  float* Zg = (float*)d_ws;                         // [bl*T][16], 221 KB
  float* Pg = Zg + (size_t)BB * LL * TT * 16;       // [bl][t][3][c], 1.3 MB

  k_Z   <<<dim3(BB * LL * TT), 64,  0, stream>>>(xl, xh, Zg);
  k_soft<<<dim3(BB * LL),      256, 0, stream>>>(xl, Zg, Wm, bm, Wq, bq, Wc, Pg);
  k_out <<<dim3(BB * LL, 4),   512, 0, stream>>>(xl, xh, Pg, Wq, bq, bc, out);
}

// Round 10
// 124.057 us; speedup vs baseline: 3.4960x; 1.0816x over previous
//
#include <hip/hip_runtime.h>
#include <math.h>

// Problem constants (fixed by the reference).
#define BB 8
#define LL 12
#define TT 36
#define DD 1024
#define CC 32

// ---------------------------------------------------------------------------
// K1: Z[t,f,g] = sum_d xh[t,d,f]*xl[d,g] (9) and H[t,f] = sum_d xh[t,d,f] (3)
// per (bl,t). One wave per block, 3456 blocks; lane owns 16 d, 24 float4
// loads in one batch, 12-value shuffle reduction, lane 0 stores 48 B.
// t==0 blocks additionally emit XLs[bl][g] = sum_d xl[d,g] (for k_out's
// K-term; replaces the separate k_soft kernel's block reduction).
// ---------------------------------------------------------------------------
__global__ __launch_bounds__(64) void k_Z(const float* __restrict__ xl,
                                          const float* __restrict__ xh,
                                          float* __restrict__ Zg,
                                          float* __restrict__ XLg) {
  const int blk  = blockIdx.x;          // bl*TT + t
  const int bl   = blk / TT;
  const int lane = threadIdx.x;         // 0..63
  const float4* xh4 = (const float4*)xh + (size_t)blk * 768 + lane * 12;
  const float4* xl4 = (const float4*)xl + (size_t)bl  * 768 + lane * 12;

  float4 a4[12], b4[12];                // 24 loads in flight together
  #pragma unroll
  for (int i = 0; i < 12; ++i) a4[i] = xh4[i];
  #pragma unroll
  for (int i = 0; i < 12; ++i) b4[i] = xl4[i];

  float Z00=0,Z01=0,Z02=0,Z10=0,Z11=0,Z12=0,Z20=0,Z21=0,Z22=0;
  float H0=0,H1=0,H2=0;
  const float* a = (const float*)a4;
  const float* b = (const float*)b4;
  #pragma unroll
  for (int k = 0; k < 16; ++k) {
    const float x0=a[k*3], x1=a[k*3+1], x2=a[k*3+2];
    const float y0=b[k*3], y1=b[k*3+1], y2=b[k*3+2];
    Z00 = fmaf(x0,y0,Z00); Z01 = fmaf(x0,y1,Z01); Z02 = fmaf(x0,y2,Z02);
    Z10 = fmaf(x1,y0,Z10); Z11 = fmaf(x1,y1,Z11); Z12 = fmaf(x1,y2,Z12);
    Z20 = fmaf(x2,y0,Z20); Z21 = fmaf(x2,y1,Z21); Z22 = fmaf(x2,y2,Z22);
    H0 += x0; H1 += x1; H2 += x2;
  }

  float v[12] = {Z00,Z01,Z02,Z10,Z11,Z12,Z20,Z21,Z22,H0,H1,H2};
  #pragma unroll
  for (int off = 32; off > 0; off >>= 1)
    #pragma unroll
    for (int j = 0; j < 12; ++j) v[j] += __shfl_down(v[j], off);

  if (lane == 0) {
    float4* o = (float4*)(Zg + (size_t)blk * 16);
    o[0] = make_float4(v[0], v[1], v[2],  v[3]);
    o[1] = make_float4(v[4], v[5], v[6],  v[7]);
    o[2] = make_float4(v[8], v[9], v[10], v[11]);
  }

  if (blk == bl * TT) {                 // t == 0: also reduce xl -> XLs
    float s0=0.f, s1=0.f, s2=0.f;
    #pragma unroll
    for (int k = 0; k < 16; ++k) {
      s0 += b[k*3]; s1 += b[k*3+1]; s2 += b[k*3+2];
    }
    #pragma unroll
    for (int off = 32; off > 0; off >>= 1) {
      s0 += __shfl_down(s0, off);
      s1 += __shfl_down(s1, off);
      s2 += __shfl_down(s2, off);
    }
    if (lane == 0) {
      XLg[bl*4+0] = s0; XLg[bl*4+1] = s1; XLg[bl*4+2] = s2;
    }
  }
}

// ---------------------------------------------------------------------------
// K2 (merged): per-block softmax prologue from Zg (tiny, redundant 8x per bl)
// then o[c,d] = sum_t sum_f att[t,c]*Wc[c,f]*xh[t,d,f]; out = o + bc + q.
// grid (96, 8) = 768 blocks = EXACTLY 3 blocks/CU (R9's 384 blocks gave
// 1.5/CU -> 2:1 CU imbalance). 256 thr = (g = tid&31: 4-d group of the
// 128-d slice) x (h5 = tid>>5: 4 channels). Half-wave coalesced xh loads
// (512B/instr), ring-3 register prefetch, P in LDS as [t][f][c4] float4
// (2 distinct addrs/wave = free broadcast). acc[4][4] = 16 regs.
// ---------------------------------------------------------------------------
__global__ __launch_bounds__(256) void k_out(const float* __restrict__ xl,
                                             const float* __restrict__ xh,
                                             const float* __restrict__ Zg,
                                             const float* __restrict__ XLg,
                                             const float* __restrict__ Wm,
                                             const float* __restrict__ bm,
                                             const float* __restrict__ Wq,
                                             const float* __restrict__ bq,
                                             const float* __restrict__ Wc,
                                             const float* __restrict__ bc,
                                             float* __restrict__ out) {
  __shared__ __align__(16) float ZS[TT * 16];     // 2.3 KB
  __shared__ float S[TT][CC];                     // 4.6 KB
  __shared__ __align__(16) float PS[TT * 3 * CC]; // 13.8 KB
  __shared__ float mxv[CC], inv[CC];
  const int bl = blockIdx.x;
  const int b = bl / LL, l = bl % LL;
  const int dh = blockIdx.y;            // 0..7 (128-d slice)
  const int tid = threadIdx.x;
  const int c = tid & 31;               // channel for prologue loops

  if (tid < TT * 4) ((float4*)ZS)[tid] = ((const float4*)(Zg + (size_t)bl * TT * 16))[tid];
  __syncthreads();

  {                                     // S[t][c] = relu(mq[c,t]) from Z/H
    const float XL0 = XLg[bl*4+0], XL1 = XLg[bl*4+1], XL2 = XLg[bl*4+2];
    const float wm0 = Wm[c*3], wm1 = Wm[c*3+1], wm2 = Wm[c*3+2];
    const float wq0 = Wq[c*3], wq1 = Wq[c*3+1], wq2 = Wq[c*3+2];
    const float bqv = bq[c], bmv = bm[c];
    const float K = bmv * (fmaf(wq0, XL0, fmaf(wq1, XL1, wq2 * XL2)) + 1024.f * bqv);
    for (int idx = tid; idx < TT * CC; idx += 256) {
      const int t = idx >> 5;           // c == tid&31 for every iteration
      const float* z = &ZS[t * 16];
      float m = K;
      m = fmaf(wm0, fmaf(wq0, z[0], fmaf(wq1, z[1], fmaf(wq2, z[2], bqv * z[9]))),  m);
      m = fmaf(wm1, fmaf(wq0, z[3], fmaf(wq1, z[4], fmaf(wq2, z[5], bqv * z[10]))), m);
      m = fmaf(wm2, fmaf(wq0, z[6], fmaf(wq1, z[7], fmaf(wq2, z[8], bqv * z[11]))), m);
      S[t][c] = fmaxf(m, 0.f);
    }
  }
  __syncthreads();

  if (tid < CC) {
    float mx = 0.f;                     // relu >= 0 -> valid seed
    #pragma unroll
    for (int t = 0; t < TT; ++t) mx = fmaxf(mx, S[t][tid]);
    float ssum = 0.f;
    #pragma unroll
    for (int t = 0; t < TT; ++t) ssum += __expf(S[t][tid] - mx);
    mxv[tid] = mx;
    inv[tid] = 1.f / ssum;
  }
  __syncthreads();

  {                                     // P[t][f][c] = att * Wc[c][f]
    const float wc0 = Wc[c*3], wc1 = Wc[c*3+1], wc2 = Wc[c*3+2];
    const float mxc = mxv[c], invc = inv[c];
    for (int idx = tid; idx < TT * CC; idx += 256) {
      const int t = idx >> 5;
      const float e = __expf(S[t][c] - mxc) * invc;
      PS[(t*3+0)*CC + c] = e * wc0;
      PS[(t*3+1)*CC + c] = e * wc1;
      PS[(t*3+2)*CC + c] = e * wc2;
    }
  }
  __syncthreads();

  const int g  = tid & 31;              // 4-d group within the 128-d slice
  const int h5 = tid >> 5;              // 0..7 -> 4 channels
  const int c0 = h5 * 4;
  const int dg = dh * 32 + g;           // global 4-d group (0..255)

  const float4* base = (const float4*)xh + (size_t)bl * TT * 768 + dg * 3;
  float4 buf[3][3];
  #pragma unroll
  for (int j = 0; j < 3; ++j)
    #pragma unroll
    for (int i = 0; i < 3; ++i) buf[j][i] = base[(size_t)j * 768 + i];

  float acc[4][4];
  #pragma unroll
  for (int u = 0; u < 4; ++u)
    #pragma unroll
    for (int dd = 0; dd < 4; ++dd) acc[u][dd] = 0.f;

  const float4* PS4 = (const float4*)PS;
  #pragma unroll
  for (int t = 0; t < TT; ++t) {
    const int sl = t % 3;               // compile-time under full unroll
    float xv[12];
    {
      const float* x = (const float*)buf[sl];
      #pragma unroll
      for (int i = 0; i < 12; ++i) xv[i] = x[i];
    }
    if (t + 3 < TT) {                   // ring prefetch, 3 t ahead
      const float4* p = base + (size_t)(t + 3) * 768;
      #pragma unroll
      for (int i = 0; i < 3; ++i) buf[sl][i] = p[i];
    }
    const float4 P0 = PS4[(t*3+0)*8 + h5];   // 2 addrs/wave: free broadcast
    const float4 P1 = PS4[(t*3+1)*8 + h5];
    const float4 P2 = PS4[(t*3+2)*8 + h5];
    const float p0[4] = {P0.x, P0.y, P0.z, P0.w};
    const float p1[4] = {P1.x, P1.y, P1.z, P1.w};
    const float p2[4] = {P2.x, P2.y, P2.z, P2.w};
    #pragma unroll
    for (int u = 0; u < 4; ++u)
      #pragma unroll
      for (int dd = 0; dd < 4; ++dd)
        acc[u][dd] = fmaf(p0[u], xv[dd*3],
                     fmaf(p1[u], xv[dd*3+1],
                     fmaf(p2[u], xv[dd*3+2], acc[u][dd])));
  }

  // Epilogue: + bc (sum att = 1) + residual q; float4 stores.
  float4 ql[3];
  {
    const float4* xl4 = (const float4*)xl + (size_t)bl * 768 + dg * 3;
    #pragma unroll
    for (int i = 0; i < 3; ++i) ql[i] = xl4[i];
  }
  const float* y = (const float*)ql;    // 12 floats = 4 d x 3 f
  #pragma unroll
  for (int u = 0; u < 4; ++u) {
    const int cc = c0 + u;
    const float w0 = Wq[cc*3], w1 = Wq[cc*3+1], w2 = Wq[cc*3+2];
    const float b0 = bq[cc], bcv = bc[cc];
    float4 o;
    o.x = acc[u][0] + bcv + fmaf(w0, y[0], fmaf(w1, y[1],  fmaf(w2, y[2],  b0)));
    o.y = acc[u][1] + bcv + fmaf(w0, y[3], fmaf(w1, y[4],  fmaf(w2, y[5],  b0)));
    o.z = acc[u][2] + bcv + fmaf(w0, y[6], fmaf(w1, y[7],  fmaf(w2, y[8],  b0)));
    o.w = acc[u][3] + bcv + fmaf(w0, y[9], fmaf(w1, y[10], fmaf(w2, y[11], b0)));
    *(float4*)(out + (((size_t)b * CC + cc) * LL + l) * DD + dg * 4) = o;
  }
}

// ---------------------------------------------------------------------------
extern "C" void kernel_launch(void* const* d_in, const int* in_sizes, int n_in,
                              void* d_out, int out_size, void* d_ws, size_t ws_size,
                              hipStream_t stream) {
  const float* xl = (const float*)d_in[0];  // (B,L,D,F)
  const float* xh = (const float*)d_in[1];  // (B,L,T,D,F)
  const float* Wq = (const float*)d_in[2];
  const float* bq = (const float*)d_in[3];
  const float* Wm = (const float*)d_in[4];
  const float* bm = (const float*)d_in[5];
  const float* Wc = (const float*)d_in[6];
  const float* bc = (const float*)d_in[7];
  float* out = (float*)d_out;               // (B,C,L,D)

  float* Zg  = (float*)d_ws;                        // [bl*T][16], 221 KB
  float* XLg = Zg + (size_t)BB * LL * TT * 16;      // [bl][4], 1.5 KB

  k_Z  <<<dim3(BB * LL * TT), 64,  0, stream>>>(xl, xh, Zg, XLg);
  k_out<<<dim3(BB * LL, 8),   256, 0, stream>>>(xl, xh, Zg, XLg, Wm, bm, Wq, bq,
                                                Wc, bc, out);
}